// Round 9
// baseline (219.618 us; speedup 1.0000x reference)
//
#include <hip/hip_runtime.h>
#include <hip/hip_bf16.h>
#include <math.h>

typedef short bf16x8 __attribute__((ext_vector_type(8)));
typedef float f32x4 __attribute__((ext_vector_type(4)));

constexpr int CIN = 32, COUT = 64, D = 16, H = 32, W = 32;

// ---------------- ws layout ----------------
// [0, 884736)          : wtp bf16 [cls8][t27][co64][ci32]
// [1MB, 1MB+33554432)  : xT  bf16 [n16][id16][ih32][iw32][ci32]
constexpr size_t WS_XT_OFF = 1u << 20;
constexpr size_t WS_NEED   = WS_XT_OFF + 33554432u;

// Unit = (cls, alpha, coHalf): code = cls + alpha*8 + coH*32.
// Waves 0,1 own coH0; waves 2,3 own coH1. Tap totals (179,196,179,196).
static __device__ const unsigned char IT_CODE[48] = {
    0, 8, 16, 4, 12, 20, 3, 11, 19, 7,                       // w0 (10)
    1, 9, 17, 2, 10, 18, 5, 13, 21, 6, 14, 22, 15, 23,        // w1 (14)
    32, 40, 48, 36, 44, 52, 35, 43, 51, 39,                   // w2 (10)
    33, 41, 49, 34, 42, 50, 37, 45, 53, 38, 46, 54, 47, 55};  // w3 (14)
static __device__ const unsigned char IT_START[5] = {0, 10, 24, 34, 48};
static __device__ const unsigned char EPI_START[10] = {0, 1, 3, 5, 6, 7, 9, 11, 12, 13};
static __device__ const unsigned char EPI_CNT[10]   = {1, 2, 2, 1, 1, 2, 2, 1, 1, 2};

// Combined prep: blocks [0,2048) transpose x (4 tiles each, 1024 thr);
// blocks [2048,2480) pack weights.
__global__ __launch_bounds__(1024) void prep_all(
    const float* __restrict__ x, const float* __restrict__ w,
    unsigned short* __restrict__ xT, unsigned short* __restrict__ wtp) {
    __shared__ float tile[4][32][33];
    int tid = threadIdx.x;
    if (blockIdx.x < 2048) {
        int sub = tid >> 8, t = tid & 255;
        int tileIdx = blockIdx.x * 4 + sub;      // n*512 + id*32 + ih
        int ih = tileIdx & 31, id = (tileIdx >> 5) & 15, n = tileIdx >> 9;
        int ci = t >> 3, iwq = t & 7;
        float4 v = ((const float4*)(x + ((((size_t)n * CIN + ci) * D + id) * H + ih) * W))[iwq];
        tile[sub][ci][iwq * 4 + 0] = v.x;
        tile[sub][ci][iwq * 4 + 1] = v.y;
        tile[sub][ci][iwq * 4 + 2] = v.z;
        tile[sub][ci][iwq * 4 + 3] = v.w;
        __syncthreads();
        int iw = t >> 3, ciq = t & 7;
        ushort4 o;
        {
            __hip_bfloat16 b0 = __float2bfloat16(tile[sub][ciq * 4 + 0][iw]);
            __hip_bfloat16 b1 = __float2bfloat16(tile[sub][ciq * 4 + 1][iw]);
            __hip_bfloat16 b2 = __float2bfloat16(tile[sub][ciq * 4 + 2][iw]);
            __hip_bfloat16 b3 = __float2bfloat16(tile[sub][ciq * 4 + 3][iw]);
            o.x = *reinterpret_cast<unsigned short*>(&b0);
            o.y = *reinterpret_cast<unsigned short*>(&b1);
            o.z = *reinterpret_cast<unsigned short*>(&b2);
            o.w = *reinterpret_cast<unsigned short*>(&b3);
        }
        ((ushort4*)(xT + ((((size_t)n * D + id) * H + ih) * W) * 32))[iw * 8 + ciq] = o;
    } else {
        int idx = (blockIdx.x - 2048) * 1024 + tid;   // 442368 = 432*1024
        int ci  = idx & 31;
        int co  = (idx >> 5) & 63;
        int tt  = idx >> 11;                          // cls*27 + t
        int t   = tt % 27, cls = tt / 27;
        int td = t / 9, th = (t / 3) % 3, tw = t % 3;
        int pd = (cls >> 2) & 1, ph = (cls >> 1) & 1, pw = cls & 1;
        int kd = pd + 2 * td, kh = ph + 2 * th, kw = pw + 2 * tw;
        float v = 0.f;
        if (kd < 5 && kh < 5 && kw < 5)
            v = w[(ci * COUT + co) * 125 + kd * 25 + kh * 5 + kw];
        __hip_bfloat16 b = __float2bfloat16(v);
        wtp[idx] = *reinterpret_cast<unsigned short*>(&b);
    }
}

__device__ __forceinline__ int lpA(int wrow, int quad) {
    return wrow * 64 + ((quad ^ ((wrow >> 1) & 3)) << 4);
}

__global__ __launch_bounds__(256, 3) void main_k(
    const unsigned short* __restrict__ wtp, const unsigned short* __restrict__ xT,
    const float* __restrict__ bias, float* __restrict__ out)
{
    __shared__ unsigned short Xs[25600];   // 51200 B, granule-XOR swizzled
    int bx = blockIdx.x;                   // (n*5+d0)*10 + h0, 800 total
    int h0 = bx % 10;
    int d0 = (bx / 10) % 5;
    int n  = bx / 50;
    int tid = threadIdx.x;

    // ---- stage Xs: logical [panel25][ww32][ci32], granule g stored at g^((ww>>1)&3)
    int id0 = 3 * d0 - 1, ih0 = 3 * h0 - 1;
    for (int i = tid; i < 3200; i += 256) {
        int cb = i & 3, ww = (i >> 2) & 31, hl = (i >> 7) % 5, dd = i / 640;
        int id = id0 + dd, ih = ih0 + hl, iw = ww - 1;
        float4 v = {0.f, 0.f, 0.f, 0.f};
        if (id >= 0 && ih >= 0 && iw >= 0)
            v = ((const float4*)(xT + ((((size_t)n * D + id) * H + ih) * W + iw) * 32))[cb];
        ((float4*)Xs)[(i >> 2) * 4 + (cb ^ ((ww >> 1) & 3))] = v;
    }

    int lane = tid & 63, wv = tid >> 6;
    int l15 = lane & 15, quad = lane >> 4;
    int wv_s = __builtin_amdgcn_readfirstlane(wv);

    // B lane offset (bytes) into co-half tap tile: co = nt*16+l15, ci = quad*8
    int laneB = l15 * 64 + quad * 16;
    // A lane offsets per shift s=2-ptw (0,1,2) and mt
    int m1 = 16 + l15; if (m1 > 29) m1 = 29;
    int lp00 = lpA(l15 + 0, quad), lp01 = lpA(l15 + 1, quad), lp02 = lpA(l15 + 2, quad);
    int lp10 = lpA(m1 + 0, quad),  lp11 = lpA(m1 + 1, quad),  lp12 = lpA(m1 + 2, quad);

    f32x4 mx[2][2];
#pragma unroll
    for (int mt = 0; mt < 2; ++mt)
#pragma unroll
        for (int nt = 0; nt < 2; ++nt) mx[mt][nt] = (f32x4){-INFINITY, -INFINITY, -INFINITY, -INFINITY};

    __syncthreads();
    const char* xsb = (const char*)Xs;

    int it0 = IT_START[wv_s], it1 = IT_START[wv_s + 1];
#pragma unroll 1
    for (int ii = it0; ii < it1; ++ii) {
        int code  = __builtin_amdgcn_readfirstlane(IT_CODE[ii]);
        int cls   = code & 7;
        int alpha = (code >> 3) & 3;
        int coH   = code >> 5;
        int ntd = 3 - ((cls >> 2) & 1), nth = 3 - ((cls >> 1) & 1), ntw = 3 - (cls & 1);
        const char* tbb = (const char*)wtp + (size_t)cls * 27 * 4096 + coH * 2048 + laneB;

        f32x4 acc[3][2][2];
#pragma unroll
        for (int b = 0; b < 3; ++b)
#pragma unroll
            for (int mt = 0; mt < 2; ++mt)
#pragma unroll
                for (int nt = 0; nt < 2; ++nt) acc[b][mt][nt] = (f32x4){0.f, 0.f, 0.f, 0.f};

        const int T = ntd * nth * ntw;
        // prefetch chunk 0: tap (0,0,0)
        bf16x8 nb0 = *(const bf16x8*)(tbb);
        bf16x8 nb1 = *(const bf16x8*)(tbb + 1024);
        int ptd = 0, pth = 0, ptw = 0;
        int nQb = ((alpha + 2) * 5 + 2) * 2048;   // panel byte offset
        int nss = 2;                              // row shift s = 2-ptw

#pragma unroll 1
        for (int it = 0; it < T; ++it) {
            bf16x8 b0 = nb0, b1 = nb1;
            const int Qb = nQb, ss = nss;

            if (it + 1 < T) {
                ++ptw;
                if (ptw == ntw) { ptw = 0; ++pth; if (pth == nth) { pth = 0; ++ptd; } }
            }
            nQb = ((alpha + 2 - ptd) * 5 + (2 - pth)) * 2048;
            nss = 2 - ptw;
            const char* bq = tbb + (ptd * 9 + pth * 3 + ptw) * 4096;
            nb0 = *(const bf16x8*)(bq);
            nb1 = *(const bf16x8*)(bq + 1024);

            int lpa = ss == 0 ? lp00 : (ss == 1 ? lp01 : lp02);
            int lpb = ss == 0 ? lp10 : (ss == 1 ? lp11 : lp12);

#pragma unroll
            for (int beta = 0; beta < 3; ++beta) {
                const char* rb = xsb + Qb + beta * 2048;
                bf16x8 af0 = *(const bf16x8*)(rb + lpa);
                bf16x8 af1 = *(const bf16x8*)(rb + lpb);
                acc[beta][0][0] = __builtin_amdgcn_mfma_f32_16x16x32_bf16(af0, b0, acc[beta][0][0], 0, 0, 0);
                acc[beta][0][1] = __builtin_amdgcn_mfma_f32_16x16x32_bf16(af0, b1, acc[beta][0][1], 0, 0, 0);
                acc[beta][1][0] = __builtin_amdgcn_mfma_f32_16x16x32_bf16(af1, b0, acc[beta][1][0], 0, 0, 0);
                acc[beta][1][1] = __builtin_amdgcn_mfma_f32_16x16x32_bf16(af1, b1, acc[beta][1][1], 0, 0, 0);
            }
        }

#pragma unroll
        for (int mt = 0; mt < 2; ++mt)
#pragma unroll
            for (int nt = 0; nt < 2; ++nt)
#pragma unroll
                for (int r = 0; r < 4; ++r) {
                    float m = fmaxf(fmaxf(acc[0][mt][nt][r], acc[1][mt][nt][r]), acc[2][mt][nt][r]);
                    mx[mt][nt][r] = fmaxf(mx[mt][nt][r], m);
                }
    }

    // ---- epilogue: gamma->window fold, cross-wave max, bias, co-sum ----
    __syncthreads();                 // Xs reads done; reuse as epi buffer
    float* epi = (float*)Xs;         // [wv4][entry16][col32]
    int fsm0 = (0x3123 >> (quad * 4)) & 15;
    int fsm1 = (0x4312 >> (quad * 4)) & 15;
#pragma unroll
    for (int mt = 0; mt < 2; ++mt) {
        int fs = mt ? fsm1 : fsm0;
        int g  = mt * 4 + quad;
#pragma unroll
        for (int nt = 0; nt < 2; ++nt) {
            float a0 = mx[mt][nt][0], a1 = mx[mt][nt][1], a2 = mx[mt][nt][2], a3 = mx[mt][nt][3];
            float t01 = fmaxf(a0, a1), t012 = fmaxf(t01, a2), t0123 = fmaxf(t012, a3);
            float pA = fs == 1 ? a0 : (fs == 2 ? t01 : (fs == 3 ? t012 : t0123));
            float t23 = fmaxf(a2, a3), t123 = fmaxf(a1, t23);
            float pB = fs == 1 ? t123 : (fs == 2 ? t23 : (fs == 3 ? a3 : -INFINITY));
            epi[(wv * 16 + g * 2 + 0) * 32 + nt * 16 + l15] = pA;
            epi[(wv * 16 + g * 2 + 1) * 32 + nt * 16 + l15] = pB;
        }
    }
    __syncthreads();

    int elemBase = ((n * 5 + d0) * 10 + h0) * 10;
    int coH = lane >> 5, col = lane & 31;
    float bco = bias[lane];
#pragma unroll 1
    for (int win = wv_s; win < 10; win += 4) {
        int st = EPI_START[win], cnt = EPI_CNT[win];
        float v = -INFINITY;
        for (int w = 2 * coH; w <= 2 * coH + 1; ++w)
            for (int e = st; e < st + cnt; ++e)
                v = fmaxf(v, epi[(w * 16 + e) * 32 + col]);
        v += bco;
#pragma unroll
        for (int off = 32; off > 0; off >>= 1) v += __shfl_xor(v, off);
        if (lane == 0) out[elemBase + win] = v;
    }
}

// ---------------- fallback (round-1 kernel, no ws needed) ----------------
__global__ __launch_bounds__(256) void fused_fallback(
    const float* __restrict__ x, const float* __restrict__ wsrc,
    const float* __restrict__ bias, float* __restrict__ out)
{
    __shared__ float xs[CIN * 125];
    __shared__ float wmax[4][64];
    const int b  = blockIdx.x;
    const int w0 = b % 10, h0 = (b / 10) % 10, d0 = (b / 100) % 5, n = b / 500;
    const int tid = threadIdx.x;
    const int id0 = 3 * d0 - 1, ih0 = 3 * h0 - 1, iw0 = 3 * w0 - 1;
    for (int e = tid; e < CIN * 125; e += 256) {
        int kk = e % 5, jj = (e / 5) % 5, ii = (e / 25) % 5, c = e / 125;
        int id = id0 + ii, ih = ih0 + jj, iw = iw0 + kk;
        float v = 0.f;
        if (id >= 0 && ih >= 0 && iw >= 0)
            v = x[(((n * CIN + c) * D + id) * H + ih) * W + iw];
        xs[e] = v;
    }
    __syncthreads();
    const int lane = tid & 63, wv = tid >> 6;
    float lmax = -INFINITY;
    for (int ccls = 0; ccls < 2; ++ccls) {
        const int cls = wv * 2 + ccls;
        const int pd = (cls >> 2) & 1, ph = (cls >> 1) & 1, pw = cls & 1;
        float acc[27];
#pragma unroll
        for (int i = 0; i < 27; ++i) acc[i] = 0.f;
        for (int ci = 0; ci < CIN; ++ci) {
            float wr[27];
#pragma unroll
            for (int t = 0; t < 27; ++t) {
                int td = t / 9, th = (t / 3) % 3, tw = t % 3;
                int kd = pd + 2 * td, kh = ph + 2 * th, kw = pw + 2 * tw;
                wr[t] = (kd < 5 && kh < 5 && kw < 5)
                          ? wsrc[((ci * 64 + lane) * 125) + kd * 25 + kh * 5 + kw] : 0.f;
            }
            const float* xb = xs + ci * 125;
#pragma unroll
            for (int td = 0; td < 3; ++td)
#pragma unroll
            for (int th = 0; th < 3; ++th)
#pragma unroll
            for (int tw = 0; tw < 3; ++tw) {
                const float wval = wr[(td * 3 + th) * 3 + tw];
#pragma unroll
                for (int a = 0; a < 3; ++a)
#pragma unroll
                for (int bb = 0; bb < 3; ++bb)
#pragma unroll
                for (int cc = 0; cc < 3; ++cc)
                    acc[(a * 3 + bb) * 3 + cc] +=
                        xb[(a + 2 - td) * 25 + (bb + 2 - th) * 5 + (cc + 2 - tw)] * wval;
            }
        }
#pragma unroll
        for (int i = 0; i < 27; ++i) lmax = fmaxf(lmax, acc[i]);
    }
    wmax[wv][lane] = lmax;
    __syncthreads();
    if (wv == 0) {
        float m = fmaxf(fmaxf(wmax[0][lane], wmax[1][lane]),
                        fmaxf(wmax[2][lane], wmax[3][lane]));
        m += bias[lane];
        for (int off = 32; off > 0; off >>= 1) m += __shfl_down(m, off);
        if (lane == 0) out[b] = m;
    }
}

extern "C" void kernel_launch(void* const* d_in, const int* in_sizes, int n_in,
                              void* d_out, int out_size, void* d_ws, size_t ws_size,
                              hipStream_t stream) {
    const float* x    = (const float*)d_in[0];
    const float* w    = (const float*)d_in[1];
    const float* bias = (const float*)d_in[2];
    float* out = (float*)d_out;

    if (ws_size >= WS_NEED) {
        unsigned short* wtp = (unsigned short*)d_ws;
        unsigned short* xT  = (unsigned short*)((char*)d_ws + WS_XT_OFF);
        prep_all<<<2480, 1024, 0, stream>>>(x, w, xT, wtp);
        main_k<<<800, 256, 0, stream>>>(wtp, xT, bias, out);
    } else {
        fused_fallback<<<8000, 256, 0, stream>>>(x, w, bias, out);
    }
}

// Round 10
// 206.092 us; speedup vs baseline: 1.0656x; 1.0656x over previous
//
#include <hip/hip_runtime.h>
#include <hip/hip_bf16.h>
#include <math.h>

typedef short bf16x8 __attribute__((ext_vector_type(8)));
typedef float f32x4 __attribute__((ext_vector_type(4)));

constexpr int CIN = 32, COUT = 64, D = 16, H = 32, W = 32;

// ---------------- ws layout ----------------
// [0, 884736) : wtp bf16 [cls8][t27][co64][ci32]
constexpr size_t WS_NEED = 884736u;

// Per-wave item lists (full-co): item = (cls, alpha), code = cls + alpha*8.
static __device__ const unsigned char IT_CODE[24] = {
    0, 8, 16, 3,                  // w0 (93 taps)
    1, 9, 17, 11, 19, 7,          // w1 (86)
    2, 10, 18, 5, 13, 21, 15,     // w2 (98)
    4, 12, 20, 6, 14, 22, 23};    // w3 (98)
static __device__ const unsigned char IT_START[5] = {0, 4, 10, 17, 24};
static __device__ const unsigned char EPI_START[10] = {0, 1, 3, 5, 6, 7, 9, 11, 12, 13};
static __device__ const unsigned char EPI_CNT[10]   = {1, 2, 2, 1, 1, 2, 2, 1, 1, 2};

__global__ void prep_w(const float* __restrict__ w, unsigned short* __restrict__ wtp) {
    int idx = blockIdx.x * 256 + threadIdx.x;            // 442368 total
    int ci  = idx & 31;
    int co  = (idx >> 5) & 63;
    int tt  = idx >> 11;                                  // cls*27 + t
    int t   = tt % 27, cls = tt / 27;
    int td = t / 9, th = (t / 3) % 3, tw = t % 3;
    int pd = (cls >> 2) & 1, ph = (cls >> 1) & 1, pw = cls & 1;
    int kd = pd + 2 * td, kh = ph + 2 * th, kw = pw + 2 * tw;
    float v = 0.f;
    if (kd < 5 && kh < 5 && kw < 5)
        v = w[(ci * COUT + co) * 125 + kd * 25 + kh * 5 + kw];
    __hip_bfloat16 b = __float2bfloat16(v);
    wtp[idx] = *reinterpret_cast<unsigned short*>(&b);
}

__device__ __forceinline__ int lpA(int wrow, int quad) {
    return wrow * 64 + ((quad ^ ((wrow >> 1) & 3)) << 4);
}

__global__ __launch_bounds__(256, 2) void main_k(
    const unsigned short* __restrict__ wtp, const float* __restrict__ x,
    const float* __restrict__ bias, float* __restrict__ out)
{
    __shared__ unsigned short Xs[25600];   // 51200 B, granule-XOR swizzled
    int bx = blockIdx.x;                   // (n*5+d0)*10 + h0, 800 total
    int h0 = bx % 10;
    int d0 = (bx / 10) % 5;
    int n  = bx / 50;
    int tid = threadIdx.x;

    // ---- stage Xs directly from x (fp32 -> bf16, transpose, swizzle) ----
    // logical Xs[p25][ww32][ci32]; ww maps iw = ww-1; phys granule = (ci>>3)^((ww>>1)&3)
    int id0 = 3 * d0 - 1, ih0 = 3 * h0 - 1;
    for (int u = tid; u < 6400; u += 256) {
        int q  = u & 7;            // float4 index: iw = 4q..4q+3
        int ci = (u >> 3) & 31;
        int p  = u >> 8;           // dd*5+hl
        int dd = p / 5, hl = p % 5;
        int id = id0 + dd, ih = ih0 + hl;
        float4 v = {0.f, 0.f, 0.f, 0.f};
        if (id >= 0 && ih >= 0)
            v = ((const float4*)(x + (((size_t)(n * CIN + ci) * D + id) * H + ih) * W))[q];
        unsigned short hj[4];
        {
            __hip_bfloat16 b0 = __float2bfloat16(v.x); hj[0] = *reinterpret_cast<unsigned short*>(&b0);
            __hip_bfloat16 b1 = __float2bfloat16(v.y); hj[1] = *reinterpret_cast<unsigned short*>(&b1);
            __hip_bfloat16 b2 = __float2bfloat16(v.z); hj[2] = *reinterpret_cast<unsigned short*>(&b2);
            __hip_bfloat16 b3 = __float2bfloat16(v.w); hj[3] = *reinterpret_cast<unsigned short*>(&b3);
        }
        int rowb = p * 1024;
        int cig = ci >> 3, cil = ci & 7;
#pragma unroll
        for (int j = 0; j < 4; ++j) {
            int ww = 4 * q + 1 + j;
            if (ww < 32)
                Xs[rowb + ww * 32 + ((cig ^ ((ww >> 1) & 3)) << 3) + cil] = hj[j];
        }
        if (q == 0)
            Xs[rowb + (cig << 3) + cil] = 0;   // ww=0 (iw=-1) zero pad
    }

    int lane = tid & 63, wv = tid >> 6;
    int l15 = lane & 15, quad = lane >> 4;
    int wv_s = __builtin_amdgcn_readfirstlane(wv);

    // B lane offset (bytes) into tap tile [co64][ci32]
    int laneB = l15 * 64 + quad * 16;
    // A lane offsets per shift s = 2-ptw (0,1,2) and mt
    int m1 = 16 + l15; if (m1 > 29) m1 = 29;
    int lp00 = lpA(l15 + 0, quad), lp01 = lpA(l15 + 1, quad), lp02 = lpA(l15 + 2, quad);
    int lp10 = lpA(m1 + 0, quad),  lp11 = lpA(m1 + 1, quad),  lp12 = lpA(m1 + 2, quad);

    f32x4 mx[2][4];
#pragma unroll
    for (int mt = 0; mt < 2; ++mt)
#pragma unroll
        for (int nt = 0; nt < 4; ++nt) mx[mt][nt] = (f32x4){-INFINITY, -INFINITY, -INFINITY, -INFINITY};

    __syncthreads();
    const char* xsb = (const char*)Xs;

    int it0 = IT_START[wv_s], it1 = IT_START[wv_s + 1];
#pragma unroll 1
    for (int ii = it0; ii < it1; ++ii) {
        int code  = __builtin_amdgcn_readfirstlane(IT_CODE[ii]);
        int cls   = code & 7;
        int alpha = code >> 3;
        int ntd = 3 - ((cls >> 2) & 1), nth = 3 - ((cls >> 1) & 1), ntw = 3 - (cls & 1);
        const char* tbb = (const char*)wtp + (size_t)cls * 27 * 4096 + laneB;
        const int T = ntd * nth * ntw;   // >= 8 always

        f32x4 acc[3][2][4];
#pragma unroll
        for (int b = 0; b < 3; ++b)
#pragma unroll
            for (int mt = 0; mt < 2; ++mt)
#pragma unroll
                for (int nt = 0; nt < 4; ++nt) acc[b][mt][nt] = (f32x4){0.f, 0.f, 0.f, 0.f};

        int ptd = 0, pth = 0, ptw = 0;   // state = next unissued tap
        auto adv = [&]() {
            ++ptw;
            if (ptw == ntw) { ptw = 0; ++pth; if (pth == nth) { pth = 0; ++ptd; } }
        };

        // ---- prologue: issue B for taps 0 (E) and 1 (O) ----
        int Qb_e = ((alpha + 2) * 5 + 2) * 2048, ss_e = 2;
        bf16x8 bE0 = *(const bf16x8*)(tbb);
        bf16x8 bE1 = *(const bf16x8*)(tbb + 1024);
        bf16x8 bE2 = *(const bf16x8*)(tbb + 2048);
        bf16x8 bE3 = *(const bf16x8*)(tbb + 3072);
        adv();
        int Qb_o = ((alpha + 2 - ptd) * 5 + (2 - pth)) * 2048, ss_o = 2 - ptw;
        const char* bqo = tbb + (ptd * 9 + pth * 3 + ptw) * 4096;
        bf16x8 bO0 = *(const bf16x8*)(bqo);
        bf16x8 bO1 = *(const bf16x8*)(bqo + 1024);
        bf16x8 bO2 = *(const bf16x8*)(bqo + 2048);
        bf16x8 bO3 = *(const bf16x8*)(bqo + 3072);
        adv();

#pragma unroll 1
        for (int it = 0; it < T; it += 2) {
            // ---- consume E (tap it) ----
            {
                int lpa = ss_e == 0 ? lp00 : (ss_e == 1 ? lp01 : lp02);
                int lpb = ss_e == 0 ? lp10 : (ss_e == 1 ? lp11 : lp12);
#pragma unroll
                for (int beta = 0; beta < 3; ++beta) {
                    const char* rb = xsb + Qb_e + beta * 2048;
                    bf16x8 af0 = *(const bf16x8*)(rb + lpa);
                    bf16x8 af1 = *(const bf16x8*)(rb + lpb);
                    acc[beta][0][0] = __builtin_amdgcn_mfma_f32_16x16x32_bf16(af0, bE0, acc[beta][0][0], 0, 0, 0);
                    acc[beta][0][1] = __builtin_amdgcn_mfma_f32_16x16x32_bf16(af0, bE1, acc[beta][0][1], 0, 0, 0);
                    acc[beta][0][2] = __builtin_amdgcn_mfma_f32_16x16x32_bf16(af0, bE2, acc[beta][0][2], 0, 0, 0);
                    acc[beta][0][3] = __builtin_amdgcn_mfma_f32_16x16x32_bf16(af0, bE3, acc[beta][0][3], 0, 0, 0);
                    acc[beta][1][0] = __builtin_amdgcn_mfma_f32_16x16x32_bf16(af1, bE0, acc[beta][1][0], 0, 0, 0);
                    acc[beta][1][1] = __builtin_amdgcn_mfma_f32_16x16x32_bf16(af1, bE1, acc[beta][1][1], 0, 0, 0);
                    acc[beta][1][2] = __builtin_amdgcn_mfma_f32_16x16x32_bf16(af1, bE2, acc[beta][1][2], 0, 0, 0);
                    acc[beta][1][3] = __builtin_amdgcn_mfma_f32_16x16x32_bf16(af1, bE3, acc[beta][1][3], 0, 0, 0);
                }
            }
            if (it + 2 < T) {     // re-issue E for tap it+2
                const char* bq = tbb + (ptd * 9 + pth * 3 + ptw) * 4096;
                Qb_e = ((alpha + 2 - ptd) * 5 + (2 - pth)) * 2048;
                ss_e = 2 - ptw;
                bE0 = *(const bf16x8*)(bq);
                bE1 = *(const bf16x8*)(bq + 1024);
                bE2 = *(const bf16x8*)(bq + 2048);
                bE3 = *(const bf16x8*)(bq + 3072);
                adv();
            }
            if (it + 1 < T) {
                // ---- consume O (tap it+1) ----
                {
                    int lpa = ss_o == 0 ? lp00 : (ss_o == 1 ? lp01 : lp02);
                    int lpb = ss_o == 0 ? lp10 : (ss_o == 1 ? lp11 : lp12);
#pragma unroll
                    for (int beta = 0; beta < 3; ++beta) {
                        const char* rb = xsb + Qb_o + beta * 2048;
                        bf16x8 af0 = *(const bf16x8*)(rb + lpa);
                        bf16x8 af1 = *(const bf16x8*)(rb + lpb);
                        acc[beta][0][0] = __builtin_amdgcn_mfma_f32_16x16x32_bf16(af0, bO0, acc[beta][0][0], 0, 0, 0);
                        acc[beta][0][1] = __builtin_amdgcn_mfma_f32_16x16x32_bf16(af0, bO1, acc[beta][0][1], 0, 0, 0);
                        acc[beta][0][2] = __builtin_amdgcn_mfma_f32_16x16x32_bf16(af0, bO2, acc[beta][0][2], 0, 0, 0);
                        acc[beta][0][3] = __builtin_amdgcn_mfma_f32_16x16x32_bf16(af0, bO3, acc[beta][0][3], 0, 0, 0);
                        acc[beta][1][0] = __builtin_amdgcn_mfma_f32_16x16x32_bf16(af1, bO0, acc[beta][1][0], 0, 0, 0);
                        acc[beta][1][1] = __builtin_amdgcn_mfma_f32_16x16x32_bf16(af1, bO1, acc[beta][1][1], 0, 0, 0);
                        acc[beta][1][2] = __builtin_amdgcn_mfma_f32_16x16x32_bf16(af1, bO2, acc[beta][1][2], 0, 0, 0);
                        acc[beta][1][3] = __builtin_amdgcn_mfma_f32_16x16x32_bf16(af1, bO3, acc[beta][1][3], 0, 0, 0);
                    }
                }
                if (it + 3 < T) {   // re-issue O for tap it+3
                    const char* bq = tbb + (ptd * 9 + pth * 3 + ptw) * 4096;
                    Qb_o = ((alpha + 2 - ptd) * 5 + (2 - pth)) * 2048;
                    ss_o = 2 - ptw;
                    bO0 = *(const bf16x8*)(bq);
                    bO1 = *(const bf16x8*)(bq + 1024);
                    bO2 = *(const bf16x8*)(bq + 2048);
                    bO3 = *(const bf16x8*)(bq + 3072);
                    adv();
                }
            }
        }

        // fold item into running max (same (m,co) mapping for every item)
#pragma unroll
        for (int mt = 0; mt < 2; ++mt)
#pragma unroll
            for (int nt = 0; nt < 4; ++nt)
#pragma unroll
                for (int r = 0; r < 4; ++r) {
                    float m = fmaxf(fmaxf(acc[0][mt][nt][r], acc[1][mt][nt][r]), acc[2][mt][nt][r]);
                    mx[mt][nt][r] = fmaxf(mx[mt][nt][r], m);
                }
    }

    // ---- epilogue: gamma->window fold, cross-wave max, bias, co-sum ----
    __syncthreads();                 // Xs reads done; reuse as epi buffer
    float* epi = (float*)Xs;
    int fsm0 = (0x3123 >> (quad * 4)) & 15;
    int fsm1 = (0x4312 >> (quad * 4)) & 15;
#pragma unroll
    for (int mt = 0; mt < 2; ++mt) {
        int fs = mt ? fsm1 : fsm0;
        int g  = mt * 4 + quad;
#pragma unroll
        for (int nt = 0; nt < 4; ++nt) {
            float a0 = mx[mt][nt][0], a1 = mx[mt][nt][1], a2 = mx[mt][nt][2], a3 = mx[mt][nt][3];
            float t01 = fmaxf(a0, a1), t012 = fmaxf(t01, a2), t0123 = fmaxf(t012, a3);
            float pA = fs == 1 ? a0 : (fs == 2 ? t01 : (fs == 3 ? t012 : t0123));
            float t23 = fmaxf(a2, a3), t123 = fmaxf(a1, t23);
            float pB = fs == 1 ? t123 : (fs == 2 ? t23 : (fs == 3 ? a3 : -INFINITY));
            epi[((wv * 8 + g) * 2 + 0) * 64 + nt * 16 + l15] = pA;
            epi[((wv * 8 + g) * 2 + 1) * 64 + nt * 16 + l15] = pB;
        }
    }
    __syncthreads();

    int elemBase = ((n * 5 + d0) * 10 + h0) * 10;
    float bco = bias[lane];
#pragma unroll 1
    for (int win = wv_s; win < 10; win += 4) {
        int st = EPI_START[win], cnt = EPI_CNT[win];
        float v = -INFINITY;
        for (int src = 0; src < 4; ++src)
            for (int e = st; e < st + cnt; ++e)
                v = fmaxf(v, epi[(src * 16 + e) * 64 + lane]);
        v += bco;
#pragma unroll
        for (int off = 32; off > 0; off >>= 1) v += __shfl_xor(v, off);
        if (lane == 0) out[elemBase + win] = v;
    }
}

// ---------------- fallback (round-1 kernel, no ws needed) ----------------
__global__ __launch_bounds__(256) void fused_fallback(
    const float* __restrict__ x, const float* __restrict__ wsrc,
    const float* __restrict__ bias, float* __restrict__ out)
{
    __shared__ float xs[CIN * 125];
    __shared__ float wmax[4][64];
    const int b  = blockIdx.x;
    const int w0 = b % 10, h0 = (b / 10) % 10, d0 = (b / 100) % 5, n = b / 500;
    const int tid = threadIdx.x;
    const int id0 = 3 * d0 - 1, ih0 = 3 * h0 - 1, iw0 = 3 * w0 - 1;
    for (int e = tid; e < CIN * 125; e += 256) {
        int kk = e % 5, jj = (e / 5) % 5, ii = (e / 25) % 5, c = e / 125;
        int id = id0 + ii, ih = ih0 + jj, iw = iw0 + kk;
        float v = 0.f;
        if (id >= 0 && ih >= 0 && iw >= 0)
            v = x[(((n * CIN + c) * D + id) * H + ih) * W + iw];
        xs[e] = v;
    }
    __syncthreads();
    const int lane = tid & 63, wv = tid >> 6;
    float lmax = -INFINITY;
    for (int ccls = 0; ccls < 2; ++ccls) {
        const int cls = wv * 2 + ccls;
        const int pd = (cls >> 2) & 1, ph = (cls >> 1) & 1, pw = cls & 1;
        float acc[27];
#pragma unroll
        for (int i = 0; i < 27; ++i) acc[i] = 0.f;
        for (int ci = 0; ci < CIN; ++ci) {
            float wr[27];
#pragma unroll
            for (int t = 0; t < 27; ++t) {
                int td = t / 9, th = (t / 3) % 3, tw = t % 3;
                int kd = pd + 2 * td, kh = ph + 2 * th, kw = pw + 2 * tw;
                wr[t] = (kd < 5 && kh < 5 && kw < 5)
                          ? wsrc[((ci * 64 + lane) * 125) + kd * 25 + kh * 5 + kw] : 0.f;
            }
            const float* xb = xs + ci * 125;
#pragma unroll
            for (int td = 0; td < 3; ++td)
#pragma unroll
            for (int th = 0; th < 3; ++th)
#pragma unroll
            for (int tw = 0; tw < 3; ++tw) {
                const float wval = wr[(td * 3 + th) * 3 + tw];
#pragma unroll
                for (int a = 0; a < 3; ++a)
#pragma unroll
                for (int bb = 0; bb < 3; ++bb)
#pragma unroll
                for (int cc = 0; cc < 3; ++cc)
                    acc[(a * 3 + bb) * 3 + cc] +=
                        xb[(a + 2 - td) * 25 + (bb + 2 - th) * 5 + (cc + 2 - tw)] * wval;
            }
        }
#pragma unroll
        for (int i = 0; i < 27; ++i) lmax = fmaxf(lmax, acc[i]);
    }
    wmax[wv][lane] = lmax;
    __syncthreads();
    if (wv == 0) {
        float m = fmaxf(fmaxf(wmax[0][lane], wmax[1][lane]),
                        fmaxf(wmax[2][lane], wmax[3][lane]));
        m += bias[lane];
        for (int off = 32; off > 0; off >>= 1) m += __shfl_down(m, off);
        if (lane == 0) out[b] = m;
    }
}

extern "C" void kernel_launch(void* const* d_in, const int* in_sizes, int n_in,
                              void* d_out, int out_size, void* d_ws, size_t ws_size,
                              hipStream_t stream) {
    const float* x    = (const float*)d_in[0];
    const float* w    = (const float*)d_in[1];
    const float* bias = (const float*)d_in[2];
    float* out = (float*)d_out;

    if (ws_size >= WS_NEED) {
        unsigned short* wtp = (unsigned short*)d_ws;
        prep_w<<<1728, 256, 0, stream>>>(w, wtp);
        main_k<<<800, 256, 0, stream>>>(wtp, x, bias, out);
    } else {
        fused_fallback<<<8000, 256, 0, stream>>>(x, w, bias, out);
    }
}

// Round 11
// 201.996 us; speedup vs baseline: 1.0872x; 1.0203x over previous
//
#include <hip/hip_runtime.h>
#include <hip/hip_bf16.h>
#include <math.h>

typedef short bf16x8 __attribute__((ext_vector_type(8)));
typedef float f32x4 __attribute__((ext_vector_type(4)));

constexpr int CIN = 32, COUT = 64, D = 16, H = 32, W = 32;

// ---------------- ws layout ----------------
// [0, 884736) : wtp bf16 [cls8][t27][co64][ci32]
constexpr size_t WS_NEED = 884736u;

// Per-wave item lists (full-co): item = (cls, alpha), code = cls + alpha*8.
static __device__ const unsigned char IT_CODE[24] = {
    0, 8, 16, 3,                  // w0 (93 taps)
    1, 9, 17, 11, 19, 7,          // w1 (86)
    2, 10, 18, 5, 13, 21, 15,     // w2 (98)
    4, 12, 20, 6, 14, 22, 23};    // w3 (98)
static __device__ const unsigned char IT_START[5] = {0, 4, 10, 17, 24};
static __device__ const unsigned char EPI_START[10] = {0, 1, 3, 5, 6, 7, 9, 11, 12, 13};
static __device__ const unsigned char EPI_CNT[10]   = {1, 2, 2, 1, 1, 2, 2, 1, 1, 2};

__global__ void prep_w(const float* __restrict__ w, unsigned short* __restrict__ wtp) {
    int idx = blockIdx.x * 256 + threadIdx.x;            // 442368 total
    int ci  = idx & 31;
    int co  = (idx >> 5) & 63;
    int tt  = idx >> 11;                                  // cls*27 + t
    int t   = tt % 27, cls = tt / 27;
    int td = t / 9, th = (t / 3) % 3, tw = t % 3;
    int pd = (cls >> 2) & 1, ph = (cls >> 1) & 1, pw = cls & 1;
    int kd = pd + 2 * td, kh = ph + 2 * th, kw = pw + 2 * tw;
    float v = 0.f;
    if (kd < 5 && kh < 5 && kw < 5)
        v = w[(ci * COUT + co) * 125 + kd * 25 + kh * 5 + kw];
    __hip_bfloat16 b = __float2bfloat16(v);
    wtp[idx] = *reinterpret_cast<unsigned short*>(&b);
}

__device__ __forceinline__ int lpA(int wrow, int quad) {
    return wrow * 64 + ((quad ^ ((wrow >> 1) & 3)) << 4);
}

__global__ __launch_bounds__(256, 2) void main_k(
    const unsigned short* __restrict__ wtp, const float* __restrict__ x,
    const float* __restrict__ bias, float* __restrict__ out)
{
    __shared__ unsigned short Xs[25600];   // 51200 B, granule-XOR swizzled
    int bx = blockIdx.x;                   // (n*5+d0)*10 + h0, 800 total
    int h0 = bx % 10;
    int d0 = (bx / 10) % 5;
    int n  = bx / 50;
    int tid = threadIdx.x;

    // ---- stage Xs directly from x (fp32 -> bf16, transpose, swizzle) ----
    int id0 = 3 * d0 - 1, ih0 = 3 * h0 - 1;
    for (int u = tid; u < 6400; u += 256) {
        int q  = u & 7;            // float4 index: iw = 4q..4q+3
        int ci = (u >> 3) & 31;
        int p  = u >> 8;           // dd*5+hl
        int dd = p / 5, hl = p % 5;
        int id = id0 + dd, ih = ih0 + hl;
        float4 v = {0.f, 0.f, 0.f, 0.f};
        if (id >= 0 && ih >= 0)
            v = ((const float4*)(x + (((size_t)(n * CIN + ci) * D + id) * H + ih) * W))[q];
        unsigned short hj[4];
        {
            __hip_bfloat16 b0 = __float2bfloat16(v.x); hj[0] = *reinterpret_cast<unsigned short*>(&b0);
            __hip_bfloat16 b1 = __float2bfloat16(v.y); hj[1] = *reinterpret_cast<unsigned short*>(&b1);
            __hip_bfloat16 b2 = __float2bfloat16(v.z); hj[2] = *reinterpret_cast<unsigned short*>(&b2);
            __hip_bfloat16 b3 = __float2bfloat16(v.w); hj[3] = *reinterpret_cast<unsigned short*>(&b3);
        }
        int rowb = p * 1024;
        int cig = ci >> 3, cil = ci & 7;
#pragma unroll
        for (int j = 0; j < 4; ++j) {
            int ww = 4 * q + 1 + j;
            if (ww < 32)
                Xs[rowb + ww * 32 + ((cig ^ ((ww >> 1) & 3)) << 3) + cil] = hj[j];
        }
        if (q == 0)
            Xs[rowb + (cig << 3) + cil] = 0;   // ww=0 (iw=-1) zero pad
    }

    int lane = tid & 63, wv = tid >> 6;
    int l15 = lane & 15, quad = lane >> 4;
    int wv_s = __builtin_amdgcn_readfirstlane(wv);

    int laneB = l15 * 64 + quad * 16;
    int m1 = 16 + l15; if (m1 > 29) m1 = 29;
    int lp00 = lpA(l15 + 0, quad), lp01 = lpA(l15 + 1, quad), lp02 = lpA(l15 + 2, quad);
    int lp10 = lpA(m1 + 0, quad),  lp11 = lpA(m1 + 1, quad),  lp12 = lpA(m1 + 2, quad);

    f32x4 mx[2][4];
#pragma unroll
    for (int mt = 0; mt < 2; ++mt)
#pragma unroll
        for (int nt = 0; nt < 4; ++nt) mx[mt][nt] = (f32x4){-INFINITY, -INFINITY, -INFINITY, -INFINITY};

    __syncthreads();
    const char* xsb = (const char*)Xs;

    int it0 = IT_START[wv_s], it1 = IT_START[wv_s + 1];
#pragma unroll 1
    for (int ii = it0; ii < it1; ++ii) {
        int code  = __builtin_amdgcn_readfirstlane(IT_CODE[ii]);
        int cls   = code & 7;
        int alpha = code >> 3;
        int ntd = 3 - ((cls >> 2) & 1), nth = 3 - ((cls >> 1) & 1), ntw = 3 - (cls & 1);
        const char* tbb = (const char*)wtp + (size_t)cls * 27 * 4096 + laneB;
        const int T = ntd * nth * ntw;   // >= 8 always

        f32x4 acc[3][2][4];
#pragma unroll
        for (int b = 0; b < 3; ++b)
#pragma unroll
            for (int mt = 0; mt < 2; ++mt)
#pragma unroll
                for (int nt = 0; nt < 4; ++nt) acc[b][mt][nt] = (f32x4){0.f, 0.f, 0.f, 0.f};

        int ptd = 0, pth = 0, ptw = 0;   // state = next unissued tap
        auto adv = [&]() {
            ++ptw;
            if (ptw == ntw) { ptw = 0; ++pth; if (pth == nth) { pth = 0; ++ptd; } }
        };

        // ---- prologue: load A+B for tap 0 (E) ----
        bf16x8 bE0, bE1, bE2, bE3, aE0, aE1, aE2, aE3, aE4, aE5;
        {
            int Qb = ((alpha + 2) * 5 + 2) * 2048;        // ss = 2
            bE0 = *(const bf16x8*)(tbb);
            bE1 = *(const bf16x8*)(tbb + 1024);
            bE2 = *(const bf16x8*)(tbb + 2048);
            bE3 = *(const bf16x8*)(tbb + 3072);
            const char* rb = xsb + Qb;
            aE0 = *(const bf16x8*)(rb + lp02);
            aE1 = *(const bf16x8*)(rb + lp12);
            aE2 = *(const bf16x8*)(rb + 2048 + lp02);
            aE3 = *(const bf16x8*)(rb + 2048 + lp12);
            aE4 = *(const bf16x8*)(rb + 4096 + lp02);
            aE5 = *(const bf16x8*)(rb + 4096 + lp12);
        }
        adv();
        // ---- load A+B for tap 1 (O) ----
        bf16x8 bO0, bO1, bO2, bO3, aO0, aO1, aO2, aO3, aO4, aO5;
        {
            int Qb = ((alpha + 2 - ptd) * 5 + (2 - pth)) * 2048;
            int ss = 2 - ptw;
            const char* bq = tbb + (ptd * 9 + pth * 3 + ptw) * 4096;
            bO0 = *(const bf16x8*)(bq);
            bO1 = *(const bf16x8*)(bq + 1024);
            bO2 = *(const bf16x8*)(bq + 2048);
            bO3 = *(const bf16x8*)(bq + 3072);
            int lpa = ss == 0 ? lp00 : (ss == 1 ? lp01 : lp02);
            int lpb = ss == 0 ? lp10 : (ss == 1 ? lp11 : lp12);
            const char* rb = xsb + Qb;
            aO0 = *(const bf16x8*)(rb + lpa);
            aO1 = *(const bf16x8*)(rb + lpb);
            aO2 = *(const bf16x8*)(rb + 2048 + lpa);
            aO3 = *(const bf16x8*)(rb + 2048 + lpb);
            aO4 = *(const bf16x8*)(rb + 4096 + lpa);
            aO5 = *(const bf16x8*)(rb + 4096 + lpb);
        }
        adv();

#pragma unroll 1
        for (int it = 0; it < T; it += 2) {
            // ---- consume E (tap it) ----
            acc[0][0][0] = __builtin_amdgcn_mfma_f32_16x16x32_bf16(aE0, bE0, acc[0][0][0], 0, 0, 0);
            acc[0][0][1] = __builtin_amdgcn_mfma_f32_16x16x32_bf16(aE0, bE1, acc[0][0][1], 0, 0, 0);
            acc[0][0][2] = __builtin_amdgcn_mfma_f32_16x16x32_bf16(aE0, bE2, acc[0][0][2], 0, 0, 0);
            acc[0][0][3] = __builtin_amdgcn_mfma_f32_16x16x32_bf16(aE0, bE3, acc[0][0][3], 0, 0, 0);
            acc[0][1][0] = __builtin_amdgcn_mfma_f32_16x16x32_bf16(aE1, bE0, acc[0][1][0], 0, 0, 0);
            acc[0][1][1] = __builtin_amdgcn_mfma_f32_16x16x32_bf16(aE1, bE1, acc[0][1][1], 0, 0, 0);
            acc[0][1][2] = __builtin_amdgcn_mfma_f32_16x16x32_bf16(aE1, bE2, acc[0][1][2], 0, 0, 0);
            acc[0][1][3] = __builtin_amdgcn_mfma_f32_16x16x32_bf16(aE1, bE3, acc[0][1][3], 0, 0, 0);
            acc[1][0][0] = __builtin_amdgcn_mfma_f32_16x16x32_bf16(aE2, bE0, acc[1][0][0], 0, 0, 0);
            acc[1][0][1] = __builtin_amdgcn_mfma_f32_16x16x32_bf16(aE2, bE1, acc[1][0][1], 0, 0, 0);
            acc[1][0][2] = __builtin_amdgcn_mfma_f32_16x16x32_bf16(aE2, bE2, acc[1][0][2], 0, 0, 0);
            acc[1][0][3] = __builtin_amdgcn_mfma_f32_16x16x32_bf16(aE2, bE3, acc[1][0][3], 0, 0, 0);
            acc[1][1][0] = __builtin_amdgcn_mfma_f32_16x16x32_bf16(aE3, bE0, acc[1][1][0], 0, 0, 0);
            acc[1][1][1] = __builtin_amdgcn_mfma_f32_16x16x32_bf16(aE3, bE1, acc[1][1][1], 0, 0, 0);
            acc[1][1][2] = __builtin_amdgcn_mfma_f32_16x16x32_bf16(aE3, bE2, acc[1][1][2], 0, 0, 0);
            acc[1][1][3] = __builtin_amdgcn_mfma_f32_16x16x32_bf16(aE3, bE3, acc[1][1][3], 0, 0, 0);
            acc[2][0][0] = __builtin_amdgcn_mfma_f32_16x16x32_bf16(aE4, bE0, acc[2][0][0], 0, 0, 0);
            acc[2][0][1] = __builtin_amdgcn_mfma_f32_16x16x32_bf16(aE4, bE1, acc[2][0][1], 0, 0, 0);
            acc[2][0][2] = __builtin_amdgcn_mfma_f32_16x16x32_bf16(aE4, bE2, acc[2][0][2], 0, 0, 0);
            acc[2][0][3] = __builtin_amdgcn_mfma_f32_16x16x32_bf16(aE4, bE3, acc[2][0][3], 0, 0, 0);
            acc[2][1][0] = __builtin_amdgcn_mfma_f32_16x16x32_bf16(aE5, bE0, acc[2][1][0], 0, 0, 0);
            acc[2][1][1] = __builtin_amdgcn_mfma_f32_16x16x32_bf16(aE5, bE1, acc[2][1][1], 0, 0, 0);
            acc[2][1][2] = __builtin_amdgcn_mfma_f32_16x16x32_bf16(aE5, bE2, acc[2][1][2], 0, 0, 0);
            acc[2][1][3] = __builtin_amdgcn_mfma_f32_16x16x32_bf16(aE5, bE3, acc[2][1][3], 0, 0, 0);
            if (it + 2 < T) {     // re-issue E for tap it+2
                int Qb = ((alpha + 2 - ptd) * 5 + (2 - pth)) * 2048;
                int ss = 2 - ptw;
                const char* bq = tbb + (ptd * 9 + pth * 3 + ptw) * 4096;
                bE0 = *(const bf16x8*)(bq);
                bE1 = *(const bf16x8*)(bq + 1024);
                bE2 = *(const bf16x8*)(bq + 2048);
                bE3 = *(const bf16x8*)(bq + 3072);
                int lpa = ss == 0 ? lp00 : (ss == 1 ? lp01 : lp02);
                int lpb = ss == 0 ? lp10 : (ss == 1 ? lp11 : lp12);
                const char* rb = xsb + Qb;
                aE0 = *(const bf16x8*)(rb + lpa);
                aE1 = *(const bf16x8*)(rb + lpb);
                aE2 = *(const bf16x8*)(rb + 2048 + lpa);
                aE3 = *(const bf16x8*)(rb + 2048 + lpb);
                aE4 = *(const bf16x8*)(rb + 4096 + lpa);
                aE5 = *(const bf16x8*)(rb + 4096 + lpb);
                adv();
            }
            if (it + 1 < T) {
                // ---- consume O (tap it+1) ----
                acc[0][0][0] = __builtin_amdgcn_mfma_f32_16x16x32_bf16(aO0, bO0, acc[0][0][0], 0, 0, 0);
                acc[0][0][1] = __builtin_amdgcn_mfma_f32_16x16x32_bf16(aO0, bO1, acc[0][0][1], 0, 0, 0);
                acc[0][0][2] = __builtin_amdgcn_mfma_f32_16x16x32_bf16(aO0, bO2, acc[0][0][2], 0, 0, 0);
                acc[0][0][3] = __builtin_amdgcn_mfma_f32_16x16x32_bf16(aO0, bO3, acc[0][0][3], 0, 0, 0);
                acc[0][1][0] = __builtin_amdgcn_mfma_f32_16x16x32_bf16(aO1, bO0, acc[0][1][0], 0, 0, 0);
                acc[0][1][1] = __builtin_amdgcn_mfma_f32_16x16x32_bf16(aO1, bO1, acc[0][1][1], 0, 0, 0);
                acc[0][1][2] = __builtin_amdgcn_mfma_f32_16x16x32_bf16(aO1, bO2, acc[0][1][2], 0, 0, 0);
                acc[0][1][3] = __builtin_amdgcn_mfma_f32_16x16x32_bf16(aO1, bO3, acc[0][1][3], 0, 0, 0);
                acc[1][0][0] = __builtin_amdgcn_mfma_f32_16x16x32_bf16(aO2, bO0, acc[1][0][0], 0, 0, 0);
                acc[1][0][1] = __builtin_amdgcn_mfma_f32_16x16x32_bf16(aO2, bO1, acc[1][0][1], 0, 0, 0);
                acc[1][0][2] = __builtin_amdgcn_mfma_f32_16x16x32_bf16(aO2, bO2, acc[1][0][2], 0, 0, 0);
                acc[1][0][3] = __builtin_amdgcn_mfma_f32_16x16x32_bf16(aO2, bO3, acc[1][0][3], 0, 0, 0);
                acc[1][1][0] = __builtin_amdgcn_mfma_f32_16x16x32_bf16(aO3, bO0, acc[1][1][0], 0, 0, 0);
                acc[1][1][1] = __builtin_amdgcn_mfma_f32_16x16x32_bf16(aO3, bO1, acc[1][1][1], 0, 0, 0);
                acc[1][1][2] = __builtin_amdgcn_mfma_f32_16x16x32_bf16(aO3, bO2, acc[1][1][2], 0, 0, 0);
                acc[1][1][3] = __builtin_amdgcn_mfma_f32_16x16x32_bf16(aO3, bO3, acc[1][1][3], 0, 0, 0);
                acc[2][0][0] = __builtin_amdgcn_mfma_f32_16x16x32_bf16(aO4, bO0, acc[2][0][0], 0, 0, 0);
                acc[2][0][1] = __builtin_amdgcn_mfma_f32_16x16x32_bf16(aO4, bO1, acc[2][0][1], 0, 0, 0);
                acc[2][0][2] = __builtin_amdgcn_mfma_f32_16x16x32_bf16(aO4, bO2, acc[2][0][2], 0, 0, 0);
                acc[2][0][3] = __builtin_amdgcn_mfma_f32_16x16x32_bf16(aO4, bO3, acc[2][0][3], 0, 0, 0);
                acc[2][1][0] = __builtin_amdgcn_mfma_f32_16x16x32_bf16(aO5, bO0, acc[2][1][0], 0, 0, 0);
                acc[2][1][1] = __builtin_amdgcn_mfma_f32_16x16x32_bf16(aO5, bO1, acc[2][1][1], 0, 0, 0);
                acc[2][1][2] = __builtin_amdgcn_mfma_f32_16x16x32_bf16(aO5, bO2, acc[2][1][2], 0, 0, 0);
                acc[2][1][3] = __builtin_amdgcn_mfma_f32_16x16x32_bf16(aO5, bO3, acc[2][1][3], 0, 0, 0);
                if (it + 3 < T) {   // re-issue O for tap it+3
                    int Qb = ((alpha + 2 - ptd) * 5 + (2 - pth)) * 2048;
                    int ss = 2 - ptw;
                    const char* bq = tbb + (ptd * 9 + pth * 3 + ptw) * 4096;
                    bO0 = *(const bf16x8*)(bq);
                    bO1 = *(const bf16x8*)(bq + 1024);
                    bO2 = *(const bf16x8*)(bq + 2048);
                    bO3 = *(const bf16x8*)(bq + 3072);
                    int lpa = ss == 0 ? lp00 : (ss == 1 ? lp01 : lp02);
                    int lpb = ss == 0 ? lp10 : (ss == 1 ? lp11 : lp12);
                    const char* rb = xsb + Qb;
                    aO0 = *(const bf16x8*)(rb + lpa);
                    aO1 = *(const bf16x8*)(rb + lpb);
                    aO2 = *(const bf16x8*)(rb + 2048 + lpa);
                    aO3 = *(const bf16x8*)(rb + 2048 + lpb);
                    aO4 = *(const bf16x8*)(rb + 4096 + lpa);
                    aO5 = *(const bf16x8*)(rb + 4096 + lpb);
                    adv();
                }
            }
        }

        // fold item into running max (same (m,co) mapping for every item)
#pragma unroll
        for (int mt = 0; mt < 2; ++mt)
#pragma unroll
            for (int nt = 0; nt < 4; ++nt)
#pragma unroll
                for (int r = 0; r < 4; ++r) {
                    float m = fmaxf(fmaxf(acc[0][mt][nt][r], acc[1][mt][nt][r]), acc[2][mt][nt][r]);
                    mx[mt][nt][r] = fmaxf(mx[mt][nt][r], m);
                }
    }

    // ---- epilogue: gamma->window fold, cross-wave max, bias, co-sum ----
    __syncthreads();                 // Xs reads done; reuse as epi buffer
    float* epi = (float*)Xs;
    int fsm0 = (0x3123 >> (quad * 4)) & 15;
    int fsm1 = (0x4312 >> (quad * 4)) & 15;
#pragma unroll
    for (int mt = 0; mt < 2; ++mt) {
        int fs = mt ? fsm1 : fsm0;
        int g  = mt * 4 + quad;
#pragma unroll
        for (int nt = 0; nt < 4; ++nt) {
            float a0 = mx[mt][nt][0], a1 = mx[mt][nt][1], a2 = mx[mt][nt][2], a3 = mx[mt][nt][3];
            float t01 = fmaxf(a0, a1), t012 = fmaxf(t01, a2), t0123 = fmaxf(t012, a3);
            float pA = fs == 1 ? a0 : (fs == 2 ? t01 : (fs == 3 ? t012 : t0123));
            float t23 = fmaxf(a2, a3), t123 = fmaxf(a1, t23);
            float pB = fs == 1 ? t123 : (fs == 2 ? t23 : (fs == 3 ? a3 : -INFINITY));
            epi[((wv * 8 + g) * 2 + 0) * 64 + nt * 16 + l15] = pA;
            epi[((wv * 8 + g) * 2 + 1) * 64 + nt * 16 + l15] = pB;
        }
    }
    __syncthreads();

    int elemBase = ((n * 5 + d0) * 10 + h0) * 10;
    float bco = bias[lane];
#pragma unroll 1
    for (int win = wv_s; win < 10; win += 4) {
        int st = EPI_START[win], cnt = EPI_CNT[win];
        float v = -INFINITY;
        for (int src = 0; src < 4; ++src)
            for (int e = st; e < st + cnt; ++e)
                v = fmaxf(v, epi[(src * 16 + e) * 64 + lane]);
        v += bco;
#pragma unroll
        for (int off = 32; off > 0; off >>= 1) v += __shfl_xor(v, off);
        if (lane == 0) out[elemBase + win] = v;
    }
}

// ---------------- fallback (round-1 kernel, no ws needed) ----------------
__global__ __launch_bounds__(256) void fused_fallback(
    const float* __restrict__ x, const float* __restrict__ wsrc,
    const float* __restrict__ bias, float* __restrict__ out)
{
    __shared__ float xs[CIN * 125];
    __shared__ float wmax[4][64];
    const int b  = blockIdx.x;
    const int w0 = b % 10, h0 = (b / 10) % 10, d0 = (b / 100) % 5, n = b / 500;
    const int tid = threadIdx.x;
    const int id0 = 3 * d0 - 1, ih0 = 3 * h0 - 1, iw0 = 3 * w0 - 1;
    for (int e = tid; e < CIN * 125; e += 256) {
        int kk = e % 5, jj = (e / 5) % 5, ii = (e / 25) % 5, c = e / 125;
        int id = id0 + ii, ih = ih0 + jj, iw = iw0 + kk;
        float v = 0.f;
        if (id >= 0 && ih >= 0 && iw >= 0)
            v = x[(((n * CIN + c) * D + id) * H + ih) * W + iw];
        xs[e] = v;
    }
    __syncthreads();
    const int lane = tid & 63, wv = tid >> 6;
    float lmax = -INFINITY;
    for (int ccls = 0; ccls < 2; ++ccls) {
        const int cls = wv * 2 + ccls;
        const int pd = (cls >> 2) & 1, ph = (cls >> 1) & 1, pw = cls & 1;
        float acc[27];
#pragma unroll
        for (int i = 0; i < 27; ++i) acc[i] = 0.f;
        for (int ci = 0; ci < CIN; ++ci) {
            float wr[27];
#pragma unroll
            for (int t = 0; t < 27; ++t) {
                int td = t / 9, th = (t / 3) % 3, tw = t % 3;
                int kd = pd + 2 * td, kh = ph + 2 * th, kw = pw + 2 * tw;
                wr[t] = (kd < 5 && kh < 5 && kw < 5)
                          ? wsrc[((ci * 64 + lane) * 125) + kd * 25 + kh * 5 + kw] : 0.f;
            }
            const float* xb = xs + ci * 125;
#pragma unroll
            for (int td = 0; td < 3; ++td)
#pragma unroll
            for (int th = 0; th < 3; ++th)
#pragma unroll
            for (int tw = 0; tw < 3; ++tw) {
                const float wval = wr[(td * 3 + th) * 3 + tw];
#pragma unroll
                for (int a = 0; a < 3; ++a)
#pragma unroll
                for (int bb = 0; bb < 3; ++bb)
#pragma unroll
                for (int cc = 0; cc < 3; ++cc)
                    acc[(a * 3 + bb) * 3 + cc] +=
                        xb[(a + 2 - td) * 25 + (bb + 2 - th) * 5 + (cc + 2 - tw)] * wval;
            }
        }
#pragma unroll
        for (int i = 0; i < 27; ++i) lmax = fmaxf(lmax, acc[i]);
    }
    wmax[wv][lane] = lmax;
    __syncthreads();
    if (wv == 0) {
        float m = fmaxf(fmaxf(wmax[0][lane], wmax[1][lane]),
                        fmaxf(wmax[2][lane], wmax[3][lane]));
        m += bias[lane];
        for (int off = 32; off > 0; off >>= 1) m += __shfl_down(m, off);
        if (lane == 0) out[b] = m;
    }
}

extern "C" void kernel_launch(void* const* d_in, const int* in_sizes, int n_in,
                              void* d_out, int out_size, void* d_ws, size_t ws_size,
                              hipStream_t stream) {
    const float* x    = (const float*)d_in[0];
    const float* w    = (const float*)d_in[1];
    const float* bias = (const float*)d_in[2];
    float* out = (float*)d_out;

    if (ws_size >= WS_NEED) {
        unsigned short* wtp = (unsigned short*)d_ws;
        prep_w<<<1728, 256, 0, stream>>>(w, wtp);
        main_k<<<800, 256, 0, stream>>>(wtp, x, bias, out);
    } else {
        fused_fallback<<<8000, 256, 0, stream>>>(x, w, bias, out);
    }
}